// Round 1
// baseline (259.916 us; speedup 1.0000x reference)
//
#include <hip/hip_runtime.h>

#define DEV __device__ __forceinline__

typedef __attribute__((ext_vector_type(8))) short short8;
typedef __attribute__((ext_vector_type(4))) float f32x4;

DEV short f2bf(float x) {
  unsigned u = __float_as_uint(x);
  unsigned r = (u + 0x7fffu + ((u >> 16) & 1u)) >> 16;
  return (short)r;
}
DEV float bf2f(short x) {
  return __uint_as_float(((unsigned)(unsigned short)x) << 16);
}

DEV void gload_lds16(const void* g, void* l) {
  __builtin_amdgcn_global_load_lds((const __attribute__((address_space(1))) void*)g,
                                   (__attribute__((address_space(3))) void*)l, 16, 0, 0);
}

// ---------- fp32 -> bf16 convert, 8 elems / thread ----------
__global__ __launch_bounds__(256) void cvt_bf16(const float* __restrict__ in,
                                                short* __restrict__ out, int n8) {
  int i = blockIdx.x * 256 + threadIdx.x;
  if (i >= n8) return;
  const float4* p = reinterpret_cast<const float4*>(in) + (size_t)i * 2;
  float4 a = p[0], b = p[1];
  short8 o;
  o[0] = f2bf(a.x); o[1] = f2bf(a.y); o[2] = f2bf(a.z); o[3] = f2bf(a.w);
  o[4] = f2bf(b.x); o[5] = f2bf(b.y); o[6] = f2bf(b.z); o[7] = f2bf(b.w);
  *reinterpret_cast<short8*>(out + (size_t)i * 8) = o;
}

// ---------- bf16 MFMA GEMM:  C[M,1024] = A[M,1024] @ W[1024,1024]^T ----------
// BM=128 BN=64 BK=64; 256 threads = 4 waves (2x2); wave tile 64x32 (4x2 frags).
// LDS tiles row-major [rows][64]; k-slot (16B units) XOR-swizzled by (row&7):
// linear gload_lds dest + inverse-swizzled global source + swizzled ds_read.
template <typename OutT>
__global__ __launch_bounds__(256) void gemm_bt(const short* __restrict__ A,
                                               const short* __restrict__ W,
                                               OutT* __restrict__ C, int M) {
  __shared__ short At[128 * 64];
  __shared__ short Bt[64 * 64];
  const int t = threadIdx.x;
  const int w = t >> 6;
  const int l = t & 63;
  const int lg = l >> 4, lr = l & 15;
  const int wm = w >> 1, wn = w & 1;
  const int rowBase = blockIdx.y * 128;
  const int colBase = blockIdx.x * 64;
  (void)M;

  f32x4 acc[4][2] = {};

  for (int kt = 0; kt < 16; ++kt) {
    const int k0 = kt * 64;
    __syncthreads();  // all waves done reading LDS from previous iter
#pragma unroll
    for (int i = 0; i < 4; ++i) {  // A tile: 1024 chunks of 16B, 4 issues/wave
      int c = w * 256 + i * 64 + l;
      int r = c >> 3, s = c & 7;
      const short* src = A + (size_t)(rowBase + r) * 1024 + k0 + ((s ^ (r & 7)) << 3);
      gload_lds16(src, At + (size_t)(w * 256 + i * 64) * 8);
    }
#pragma unroll
    for (int i = 0; i < 2; ++i) {  // B tile: 512 chunks, 2 issues/wave
      int c = w * 128 + i * 64 + l;
      int r = c >> 3, s = c & 7;
      const short* src = W + (size_t)(colBase + r) * 1024 + k0 + ((s ^ (r & 7)) << 3);
      gload_lds16(src, Bt + (size_t)(w * 128 + i * 64) * 8);
    }
    __syncthreads();  // vmcnt(0) drained before barrier -> LDS tiles ready
#pragma unroll
    for (int kk = 0; kk < 2; ++kk) {
      short8 bfr[2];
#pragma unroll
      for (int n = 0; n < 2; ++n) {
        int br = wn * 32 + n * 16 + lr;
        int slot = (kk * 4 + lg) ^ (br & 7);
        bfr[n] = *reinterpret_cast<const short8*>(&Bt[br * 64 + slot * 8]);
      }
#pragma unroll
      for (int m = 0; m < 4; ++m) {
        int ar = wm * 64 + m * 16 + lr;
        int slot = (kk * 4 + lg) ^ (ar & 7);
        short8 afr = *reinterpret_cast<const short8*>(&At[ar * 64 + slot * 8]);
        acc[m][0] = __builtin_amdgcn_mfma_f32_16x16x32_bf16(afr, bfr[0], acc[m][0], 0, 0, 0);
        acc[m][1] = __builtin_amdgcn_mfma_f32_16x16x32_bf16(afr, bfr[1], acc[m][1], 0, 0, 0);
      }
    }
  }
  // epilogue: C/D layout col = lane&15, row = (lane>>4)*4 + j
#pragma unroll
  for (int m = 0; m < 4; ++m)
#pragma unroll
    for (int n = 0; n < 2; ++n) {
      int row0 = rowBase + wm * 64 + m * 16 + lg * 4;
      int col = colBase + wn * 32 + n * 16 + lr;
#pragma unroll
      for (int j = 0; j < 4; ++j) {
        float v = acc[m][n][j];
        if constexpr (sizeof(OutT) == 2)
          C[(size_t)(row0 + j) * 1024 + col] = (OutT)f2bf(v);
        else
          C[(size_t)(row0 + j) * 1024 + col] = (OutT)v;
      }
    }
}

// ---------- M[b][h] = K_bh^T V_bh / 8  (fp32, split-S atomics) ----------
__global__ __launch_bounds__(256) void kv_outer(const short* __restrict__ Kp,
                                                const short* __restrict__ Vp,
                                                float* __restrict__ Mb) {
  __shared__ float Ks[128][64];
  __shared__ float Vs[128][64];
  const int t = threadIdx.x;
  const int sc = blockIdx.x, h = blockIdx.y, b = blockIdx.z;
  const size_t base = ((size_t)(b * 2048 + sc * 128)) * 1024 + h * 64;
  for (int e = t; e < 128 * 64; e += 256) {
    int r = e >> 6, c = e & 63;
    size_t g = base + (size_t)r * 1024 + c;
    Ks[r][c] = bf2f(Kp[g]);
    Vs[r][c] = bf2f(Vp[g]);
  }
  __syncthreads();
  const int dp0 = (t >> 4) * 4, d0 = (t & 15) * 4;
  float acc[4][4] = {};
  for (int s = 0; s < 128; ++s) {
    float4 kv = *reinterpret_cast<const float4*>(&Ks[s][dp0]);
    float4 vv = *reinterpret_cast<const float4*>(&Vs[s][d0]);
    float ka[4] = {kv.x, kv.y, kv.z, kv.w};
    float va[4] = {vv.x, vv.y, vv.z, vv.w};
#pragma unroll
    for (int i = 0; i < 4; ++i)
#pragma unroll
      for (int j = 0; j < 4; ++j) acc[i][j] += ka[i] * va[j];
  }
  float* dst = Mb + (size_t)(b * 16 + h) * 4096;
#pragma unroll
  for (int i = 0; i < 4; ++i)
#pragma unroll
    for (int j = 0; j < 4; ++j)
      atomicAdd(&dst[(dp0 + i) * 64 + d0 + j], acc[i][j] * 0.125f);
}

// ---------- W2T[b][j][h*64+d'] = sum_d M_bh[d'][d] * Wo[j][h*64+d]  (bf16 out) ----------
__global__ __launch_bounds__(256) void make_w2t(const float* __restrict__ Mb,
                                                const short* __restrict__ Wo,
                                                short* __restrict__ W2T) {
  __shared__ float Ms[64][65];  // +1 pad: 16 distinct rows read at same col
  __shared__ float Wos[64][64];
  const int t = threadIdx.x;
  const int jc = blockIdx.x, h = blockIdx.y, b = blockIdx.z;
  const float* Msrc = Mb + (size_t)(b * 16 + h) * 4096;
  for (int e = t; e < 4096; e += 256) {
    int r = e >> 6, c = e & 63;
    Ms[r][c] = Msrc[e];
    Wos[r][c] = bf2f(Wo[(size_t)(jc * 64 + r) * 1024 + h * 64 + c]);
  }
  __syncthreads();
  const int j0 = (t >> 4) * 4, p0 = (t & 15) * 4;
  float acc[4][4] = {};
  for (int d = 0; d < 64; ++d) {
    float wv[4], mv[4];
#pragma unroll
    for (int i = 0; i < 4; ++i) { wv[i] = Wos[j0 + i][d]; mv[i] = Ms[p0 + i][d]; }
#pragma unroll
    for (int i = 0; i < 4; ++i)
#pragma unroll
      for (int j2 = 0; j2 < 4; ++j2) acc[i][j2] += wv[i] * mv[j2];
  }
  short* dst = W2T + (size_t)b * 1048576;
#pragma unroll
  for (int i = 0; i < 4; ++i)
#pragma unroll
    for (int j2 = 0; j2 < 4; ++j2)
      dst[(size_t)(jc * 64 + j0 + i) * 1024 + h * 64 + p0 + j2] = f2bf(acc[i][j2]);
}

extern "C" void kernel_launch(void* const* d_in, const int* in_sizes, int n_in,
                              void* d_out, int out_size, void* d_ws, size_t ws_size,
                              hipStream_t stream) {
  const float* q  = (const float*)d_in[0];
  const float* k  = (const float*)d_in[1];
  const float* v  = (const float*)d_in[2];
  // d_in[3] = mask: no-op in the reference
  const float* Wq = (const float*)d_in[4];
  const float* Wk = (const float*)d_in[5];
  const float* Wv = (const float*)d_in[6];
  const float* Wo = (const float*)d_in[7];
  float* out = (float*)d_out;
  char* ws = (char*)d_ws;

  // workspace layout (44.5 MiB total)
  short* xbf = (short*)(ws);                         // 8 MiB: input staging (reused q/k/v)
  short* wqb = (short*)(ws + (8l << 20));            // 4 x 2 MiB weights
  short* wkb = wqb + 1048576;
  short* wvb = wkb + 1048576;
  short* wob = wvb + 1048576;
  short* Qp  = (short*)(ws + (16l << 20));           // 8 MiB
  short* Kp  = (short*)(ws + (24l << 20));           // 8 MiB
  short* Vp  = (short*)(ws + (32l << 20));           // 8 MiB
  float* Mb  = (float*)(ws + (40l << 20));           // 512 KiB
  short* W2T = (short*)(ws + (40l << 20) + (1l << 19)); // 4 MiB

  hipMemsetAsync(Mb, 0, 32 * 64 * 64 * sizeof(float), stream);

  cvt_bf16<<<512, 256, 0, stream>>>(Wq, wqb, 131072);
  cvt_bf16<<<512, 256, 0, stream>>>(Wk, wkb, 131072);
  cvt_bf16<<<512, 256, 0, stream>>>(Wv, wvb, 131072);
  cvt_bf16<<<512, 256, 0, stream>>>(Wo, wob, 131072);

  cvt_bf16<<<2048, 256, 0, stream>>>(q, xbf, 524288);
  gemm_bt<short><<<dim3(16, 32), 256, 0, stream>>>(xbf, wqb, Qp, 4096);
  cvt_bf16<<<2048, 256, 0, stream>>>(k, xbf, 524288);
  gemm_bt<short><<<dim3(16, 32), 256, 0, stream>>>(xbf, wkb, Kp, 4096);
  cvt_bf16<<<2048, 256, 0, stream>>>(v, xbf, 524288);
  gemm_bt<short><<<dim3(16, 32), 256, 0, stream>>>(xbf, wvb, Vp, 4096);

  kv_outer<<<dim3(16, 16, 2), 256, 0, stream>>>(Kp, Vp, Mb);
  make_w2t<<<dim3(16, 16, 2), 256, 0, stream>>>(Mb, wob, W2T);

  gemm_bt<float><<<dim3(16, 16), 256, 0, stream>>>(Qp, W2T, out, 2048);
  gemm_bt<float><<<dim3(16, 16), 256, 0, stream>>>(Qp + (size_t)2048 * 1024, W2T + 1048576,
                                                   out + (size_t)2048 * 1024, 2048);
}

// Round 2
// 217.658 us; speedup vs baseline: 1.1942x; 1.1942x over previous
//
#include <hip/hip_runtime.h>

#define DEV __device__ __forceinline__

typedef __attribute__((ext_vector_type(8))) short short8;
typedef __attribute__((ext_vector_type(4))) float f32x4;

DEV short f2bf(float x) {
  unsigned u = __float_as_uint(x);
  unsigned r = (u + 0x7fffu + ((u >> 16) & 1u)) >> 16;
  return (short)r;
}
DEV float bf2f(short x) {
  return __uint_as_float(((unsigned)(unsigned short)x) << 16);
}

DEV void gload_lds16(const void* g, void* l) {
  __builtin_amdgcn_global_load_lds((const __attribute__((address_space(1))) void*)g,
                                   (__attribute__((address_space(3))) void*)l, 16, 0, 0);
}

// ---------- fused fp32 -> bf16 convert for all 7 tensors ----------
// groups of 8 elems: q,k,v = 524288 each; Wq,Wk,Wv,Wo = 131072 each. total 2097152.
__global__ __launch_bounds__(256) void cvt_all(
    const float* __restrict__ s0, const float* __restrict__ s1,
    const float* __restrict__ s2, const float* __restrict__ s3,
    const float* __restrict__ s4, const float* __restrict__ s5,
    const float* __restrict__ s6,
    short* __restrict__ d0, short* __restrict__ d1, short* __restrict__ d2,
    short* __restrict__ d3, short* __restrict__ d4, short* __restrict__ d5,
    short* __restrict__ d6) {
  int g = blockIdx.x * 256 + threadIdx.x;
  const float* s;
  short* d;
  int off;
  if (g < 524288) { s = s0; d = d0; off = g; }
  else if (g < 1048576) { s = s1; d = d1; off = g - 524288; }
  else if (g < 1572864) { s = s2; d = d2; off = g - 1048576; }
  else {
    int w2 = g - 1572864;
    int seg = w2 >> 17;
    off = w2 & 131071;
    s = seg == 0 ? s3 : seg == 1 ? s4 : seg == 2 ? s5 : s6;
    d = seg == 0 ? d3 : seg == 1 ? d4 : seg == 2 ? d5 : d6;
  }
  const float4* p = reinterpret_cast<const float4*>(s) + (size_t)off * 2;
  float4 a = p[0], b = p[1];
  short8 o;
  o[0] = f2bf(a.x); o[1] = f2bf(a.y); o[2] = f2bf(a.z); o[3] = f2bf(a.w);
  o[4] = f2bf(b.x); o[5] = f2bf(b.y); o[6] = f2bf(b.z); o[7] = f2bf(b.w);
  *reinterpret_cast<short8*>(d + (size_t)off * 8) = o;
}

// ---------- bf16 MFMA GEMM (m97 structure): C[M,1024] = A[M,1024] @ W[1024,1024]^T ----------
// BM=BN=128, BK=64; 256 threads = 4 waves (2x2), wave tile 64x64 (4x4 frags of 16x16x32).
// z-batched via element strides. LDS row-major [row][64] bf16, k-slot (16B) XOR-swizzle
// by (row&7): linear gload_lds dest + inverse-swizzled global src + swizzled ds_read.
template <typename OutT>
__global__ __launch_bounds__(256) void gemm_bt128(const short* __restrict__ A,
                                                  const short* __restrict__ W,
                                                  OutT* __restrict__ C,
                                                  long strideA, long strideW, long strideC) {
  __shared__ short At[128 * 64];
  __shared__ short Bt[128 * 64];
  const short* Ab = A + (size_t)blockIdx.z * strideA;
  const short* Wb = W + (size_t)blockIdx.z * strideW;
  OutT* Cb = C + (size_t)blockIdx.z * strideC;
  const int t = threadIdx.x;
  const int w = t >> 6;
  const int l = t & 63;
  const int lg = l >> 4, lr = l & 15;
  const int wm = w >> 1, wn = w & 1;
  const int rowBase = blockIdx.y * 128;
  const int colBase = blockIdx.x * 128;

  f32x4 acc[4][4] = {};

  for (int kt = 0; kt < 16; ++kt) {
    const int k0 = kt * 64;
    __syncthreads();  // previous iter's LDS reads done
#pragma unroll
    for (int i = 0; i < 4; ++i) {  // 1024 16B chunks per tile, 4 per thread
      int c = w * 256 + i * 64 + l;
      int r = c >> 3, s = c & 7;
      int goff = k0 + ((s ^ (r & 7)) << 3);
      gload_lds16(Ab + (size_t)(rowBase + r) * 1024 + goff, At + (size_t)c * 8);
      gload_lds16(Wb + (size_t)(colBase + r) * 1024 + goff, Bt + (size_t)c * 8);
    }
    __syncthreads();  // compiler drains vmcnt(0) before barrier -> tiles ready
#pragma unroll
    for (int kk = 0; kk < 2; ++kk) {
      short8 afr[4], bfr[4];
#pragma unroll
      for (int m = 0; m < 4; ++m) {
        int ar = wm * 64 + m * 16 + lr;
        int slot = (kk * 4 + lg) ^ (ar & 7);
        afr[m] = *reinterpret_cast<const short8*>(&At[ar * 64 + slot * 8]);
      }
#pragma unroll
      for (int n = 0; n < 4; ++n) {
        int br = wn * 64 + n * 16 + lr;
        int slot = (kk * 4 + lg) ^ (br & 7);
        bfr[n] = *reinterpret_cast<const short8*>(&Bt[br * 64 + slot * 8]);
      }
#pragma unroll
      for (int m = 0; m < 4; ++m)
#pragma unroll
        for (int n = 0; n < 4; ++n)
          acc[m][n] = __builtin_amdgcn_mfma_f32_16x16x32_bf16(afr[m], bfr[n], acc[m][n], 0, 0, 0);
    }
  }
  // epilogue: C/D layout col = lane&15, row = (lane>>4)*4 + j
#pragma unroll
  for (int m = 0; m < 4; ++m)
#pragma unroll
    for (int n = 0; n < 4; ++n) {
      int row0 = rowBase + wm * 64 + m * 16 + lg * 4;
      int col = colBase + wn * 64 + n * 16 + lr;
#pragma unroll
      for (int j = 0; j < 4; ++j) {
        float v = acc[m][n][j];
        if constexpr (sizeof(OutT) == 2)
          Cb[(size_t)(row0 + j) * 1024 + col] = (OutT)f2bf(v);
        else
          Cb[(size_t)(row0 + j) * 1024 + col] = (OutT)v;
      }
    }
}

// ---------- M[b][h] = K_bh^T V_bh / 8  (fp32, split-S atomics) ----------
__global__ __launch_bounds__(256) void kv_outer(const short* __restrict__ Kp,
                                                const short* __restrict__ Vp,
                                                float* __restrict__ Mb) {
  __shared__ float Ks[128][64];
  __shared__ float Vs[128][64];
  const int t = threadIdx.x;
  const int sc = blockIdx.x, h = blockIdx.y, b = blockIdx.z;
  const size_t base = ((size_t)(b * 2048 + sc * 128)) * 1024 + h * 64;
  for (int e = t; e < 128 * 64; e += 256) {
    int r = e >> 6, c = e & 63;
    size_t g = base + (size_t)r * 1024 + c;
    Ks[r][c] = bf2f(Kp[g]);
    Vs[r][c] = bf2f(Vp[g]);
  }
  __syncthreads();
  const int dp0 = (t >> 4) * 4, d0 = (t & 15) * 4;
  float acc[4][4] = {};
  for (int s = 0; s < 128; ++s) {
    float4 kv = *reinterpret_cast<const float4*>(&Ks[s][dp0]);
    float4 vv = *reinterpret_cast<const float4*>(&Vs[s][d0]);
    float ka[4] = {kv.x, kv.y, kv.z, kv.w};
    float va[4] = {vv.x, vv.y, vv.z, vv.w};
#pragma unroll
    for (int i = 0; i < 4; ++i)
#pragma unroll
      for (int j = 0; j < 4; ++j) acc[i][j] += ka[i] * va[j];
  }
  float* dst = Mb + (size_t)(b * 16 + h) * 4096;
#pragma unroll
  for (int i = 0; i < 4; ++i)
#pragma unroll
    for (int j = 0; j < 4; ++j)
      atomicAdd(&dst[(dp0 + i) * 64 + d0 + j], acc[i][j] * 0.125f);
}

// ---------- W2T[b][j][h*64+d'] = sum_d M_bh[d'][d] * Wo[j][h*64+d]  (bf16 out) ----------
__global__ __launch_bounds__(256) void make_w2t(const float* __restrict__ Mb,
                                                const short* __restrict__ Wo,
                                                short* __restrict__ W2T) {
  __shared__ float Ms[64][65];
  __shared__ float Wos[64][64];
  const int t = threadIdx.x;
  const int jc = blockIdx.x, h = blockIdx.y, b = blockIdx.z;
  const float* Msrc = Mb + (size_t)(b * 16 + h) * 4096;
  for (int e = t; e < 4096; e += 256) {
    int r = e >> 6, c = e & 63;
    Ms[r][c] = Msrc[e];
    Wos[r][c] = bf2f(Wo[(size_t)(jc * 64 + r) * 1024 + h * 64 + c]);
  }
  __syncthreads();
  const int j0 = (t >> 4) * 4, p0 = (t & 15) * 4;
  float acc[4][4] = {};
  for (int d = 0; d < 64; ++d) {
    float wv[4], mv[4];
#pragma unroll
    for (int i = 0; i < 4; ++i) { wv[i] = Wos[j0 + i][d]; mv[i] = Ms[p0 + i][d]; }
#pragma unroll
    for (int i = 0; i < 4; ++i)
#pragma unroll
      for (int j2 = 0; j2 < 4; ++j2) acc[i][j2] += wv[i] * mv[j2];
  }
  short* dst = W2T + (size_t)b * 1048576;
#pragma unroll
  for (int i = 0; i < 4; ++i)
#pragma unroll
    for (int j2 = 0; j2 < 4; ++j2)
      dst[(size_t)(jc * 64 + j0 + i) * 1024 + h * 64 + p0 + j2] = f2bf(acc[i][j2]);
}

extern "C" void kernel_launch(void* const* d_in, const int* in_sizes, int n_in,
                              void* d_out, int out_size, void* d_ws, size_t ws_size,
                              hipStream_t stream) {
  const float* q  = (const float*)d_in[0];
  const float* k  = (const float*)d_in[1];
  const float* v  = (const float*)d_in[2];
  // d_in[3] = mask: no-op in the reference
  const float* Wq = (const float*)d_in[4];
  const float* Wk = (const float*)d_in[5];
  const float* Wv = (const float*)d_in[6];
  const float* Wo = (const float*)d_in[7];
  float* out = (float*)d_out;
  char* ws = (char*)d_ws;

  // workspace layout (~62 MiB)
  short* qkv = (short*)(ws);                  // 24 MiB: q,k,v bf16 contiguous (4M elems each)
  short* qb = qkv;
  short* kb = qkv + (size_t)4194304;
  short* vb = qkv + (size_t)8388608;
  short* wb = (short*)(ws + (24l << 20));     // 8 MiB: Wq,Wk,Wv,Wo bf16 (1M elems each)
  short* wqb = wb;
  short* wkb = wb + 1048576;
  short* wvb = wb + 2097152;
  short* wob = wb + 3145728;
  short* Pp = (short*)(ws + (32l << 20));     // 24 MiB: Qp,Kp,Vp contiguous
  short* Qp = Pp;
  short* Kp = Pp + (size_t)4194304;
  short* Vp = Pp + (size_t)8388608;
  float* Mb  = (float*)(ws + (56l << 20));    // 512 KiB
  short* W2T = (short*)(ws + (57l << 20));    // 4 MiB

  hipMemsetAsync(Mb, 0, 32 * 64 * 64 * sizeof(float), stream);

  cvt_all<<<8192, 256, 0, stream>>>(q, k, v, Wq, Wk, Wv, Wo,
                                    qb, kb, vb, wqb, wkb, wvb, wob);

  // Q/K/V projections in one z-batched launch
  gemm_bt128<short><<<dim3(8, 32, 3), 256, 0, stream>>>(
      qkv, wb, Pp, 4194304l, 1048576l, 4194304l);

  kv_outer<<<dim3(16, 16, 2), 256, 0, stream>>>(Kp, Vp, Mb);
  make_w2t<<<dim3(16, 16, 2), 256, 0, stream>>>(Mb, wob, W2T);

  // out[b] = Qp[b] @ W2T[b]^T, both batches in one launch
  gemm_bt128<float><<<dim3(8, 16, 2), 256, 0, stream>>>(
      Qp, W2T, out, 2097152l, 1048576l, 2097152l);
}

// Round 3
// 212.464 us; speedup vs baseline: 1.2233x; 1.0244x over previous
//
#include <hip/hip_runtime.h>

#define DEV __device__ __forceinline__

typedef __attribute__((ext_vector_type(8))) short short8;
typedef __attribute__((ext_vector_type(4))) float f32x4;

DEV short f2bf(float x) {
  unsigned u = __float_as_uint(x);
  unsigned r = (u + 0x7fffu + ((u >> 16) & 1u)) >> 16;
  return (short)r;
}
DEV float bf2f(short x) {
  return __uint_as_float(((unsigned)(unsigned short)x) << 16);
}

DEV void gload_lds16(const void* g, void* l) {
  __builtin_amdgcn_global_load_lds((const __attribute__((address_space(1))) void*)g,
                                   (__attribute__((address_space(3))) void*)l, 16, 0, 0);
}

// ---------- fused fp32 -> bf16 convert for all 7 tensors + zero-init of Mb ----------
// groups of 8 elems: q,k,v = 524288 each; Wq,Wk,Wv,Wo = 131072 each (total 2097152),
// then 16384 zero-groups for Mb (131072 floats).
__global__ __launch_bounds__(256) void cvt_all(
    const float* __restrict__ s0, const float* __restrict__ s1,
    const float* __restrict__ s2, const float* __restrict__ s3,
    const float* __restrict__ s4, const float* __restrict__ s5,
    const float* __restrict__ s6,
    short* __restrict__ d0, short* __restrict__ d1, short* __restrict__ d2,
    short* __restrict__ d3, short* __restrict__ d4, short* __restrict__ d5,
    short* __restrict__ d6, float* __restrict__ Mb) {
  int g = blockIdx.x * 256 + threadIdx.x;
  if (g >= 2097152) {  // Mb zero-init (needed by kv_outer atomics; ws is poisoned 0xAA)
    int off = g - 2097152;
    float4 z = {0.f, 0.f, 0.f, 0.f};
    float4* p = reinterpret_cast<float4*>(Mb) + (size_t)off * 2;
    p[0] = z;
    p[1] = z;
    return;
  }
  const float* s;
  short* d;
  int off;
  if (g < 524288) { s = s0; d = d0; off = g; }
  else if (g < 1048576) { s = s1; d = d1; off = g - 524288; }
  else if (g < 1572864) { s = s2; d = d2; off = g - 1048576; }
  else {
    int w2 = g - 1572864;
    int seg = w2 >> 17;
    off = w2 & 131071;
    s = seg == 0 ? s3 : seg == 1 ? s4 : seg == 2 ? s5 : s6;
    d = seg == 0 ? d3 : seg == 1 ? d4 : seg == 2 ? d5 : d6;
  }
  const float4* p = reinterpret_cast<const float4*>(s) + (size_t)off * 2;
  float4 a = p[0], b = p[1];
  short8 o;
  o[0] = f2bf(a.x); o[1] = f2bf(a.y); o[2] = f2bf(a.z); o[3] = f2bf(a.w);
  o[4] = f2bf(b.x); o[5] = f2bf(b.y); o[6] = f2bf(b.z); o[7] = f2bf(b.w);
  *reinterpret_cast<short8*>(d + (size_t)off * 8) = o;
}

// ---------- bf16 MFMA GEMM (m97 structure): C[M,1024] = A[M,1024] @ W[1024,1024]^T ----------
// BM=BN=128, BK=64; 256 threads = 4 waves (2x2), wave tile 64x64 (4x4 frags of 16x16x32).
// z-batched via element strides. LDS row-major [row][64] bf16, k-slot (16B) XOR-swizzle
// by (row&7): linear gload_lds dest + inverse-swizzled global src + swizzled ds_read.
template <typename OutT>
__global__ __launch_bounds__(256) void gemm_bt128(const short* __restrict__ A,
                                                  const short* __restrict__ W,
                                                  OutT* __restrict__ C,
                                                  long strideA, long strideW, long strideC) {
  __shared__ short At[128 * 64];
  __shared__ short Bt[128 * 64];
  const short* Ab = A + (size_t)blockIdx.z * strideA;
  const short* Wb = W + (size_t)blockIdx.z * strideW;
  OutT* Cb = C + (size_t)blockIdx.z * strideC;
  const int t = threadIdx.x;
  const int w = t >> 6;
  const int l = t & 63;
  const int lg = l >> 4, lr = l & 15;
  const int wm = w >> 1, wn = w & 1;
  const int rowBase = blockIdx.y * 128;
  const int colBase = blockIdx.x * 128;

  f32x4 acc[4][4] = {};

  for (int kt = 0; kt < 16; ++kt) {
    const int k0 = kt * 64;
    __syncthreads();  // previous iter's LDS reads done
#pragma unroll
    for (int i = 0; i < 4; ++i) {  // 1024 16B chunks per tile, 4 per thread
      int c = w * 256 + i * 64 + l;
      int r = c >> 3, s = c & 7;
      int goff = k0 + ((s ^ (r & 7)) << 3);
      gload_lds16(Ab + (size_t)(rowBase + r) * 1024 + goff, At + (size_t)c * 8);
      gload_lds16(Wb + (size_t)(colBase + r) * 1024 + goff, Bt + (size_t)c * 8);
    }
    __syncthreads();  // compiler drains vmcnt(0) before barrier -> tiles ready
#pragma unroll
    for (int kk = 0; kk < 2; ++kk) {
      short8 afr[4], bfr[4];
#pragma unroll
      for (int m = 0; m < 4; ++m) {
        int ar = wm * 64 + m * 16 + lr;
        int slot = (kk * 4 + lg) ^ (ar & 7);
        afr[m] = *reinterpret_cast<const short8*>(&At[ar * 64 + slot * 8]);
      }
#pragma unroll
      for (int n = 0; n < 4; ++n) {
        int br = wn * 64 + n * 16 + lr;
        int slot = (kk * 4 + lg) ^ (br & 7);
        bfr[n] = *reinterpret_cast<const short8*>(&Bt[br * 64 + slot * 8]);
      }
#pragma unroll
      for (int m = 0; m < 4; ++m)
#pragma unroll
        for (int n = 0; n < 4; ++n)
          acc[m][n] = __builtin_amdgcn_mfma_f32_16x16x32_bf16(afr[m], bfr[n], acc[m][n], 0, 0, 0);
    }
  }
  // epilogue: C/D layout col = lane&15, row = (lane>>4)*4 + j
#pragma unroll
  for (int m = 0; m < 4; ++m)
#pragma unroll
    for (int n = 0; n < 4; ++n) {
      int row0 = rowBase + wm * 64 + m * 16 + lg * 4;
      int col = colBase + wn * 64 + n * 16 + lr;
#pragma unroll
      for (int j = 0; j < 4; ++j) {
        float v = acc[m][n][j];
        if constexpr (sizeof(OutT) == 2)
          Cb[(size_t)(row0 + j) * 1024 + col] = (OutT)f2bf(v);
        else
          Cb[(size_t)(row0 + j) * 1024 + col] = (OutT)v;
      }
    }
}

// ---------- bf16 MFMA GEMM, 128x64 tile (2+ blocks/CU for occupancy-bound shapes) ----------
// BM=128 BN=64 BK=64; 256 threads = 4 waves (2x2); wave tile 64x32 (4x2 frags).
// Same swizzle scheme as gemm_bt128. Used for the final GEMM (grid would be 1 block/CU
// at 128x128; this tile doubles resident blocks -> hides the barrier-drain stall).
template <typename OutT>
__global__ __launch_bounds__(256) void gemm_bt64(const short* __restrict__ A,
                                                 const short* __restrict__ W,
                                                 OutT* __restrict__ C,
                                                 long strideA, long strideW, long strideC) {
  __shared__ short At[128 * 64];
  __shared__ short Bt[64 * 64];
  const short* Ab = A + (size_t)blockIdx.z * strideA;
  const short* Wb = W + (size_t)blockIdx.z * strideW;
  OutT* Cb = C + (size_t)blockIdx.z * strideC;
  const int t = threadIdx.x;
  const int w = t >> 6;
  const int l = t & 63;
  const int lg = l >> 4, lr = l & 15;
  const int wm = w >> 1, wn = w & 1;
  const int rowBase = blockIdx.y * 128;
  const int colBase = blockIdx.x * 64;

  f32x4 acc[4][2] = {};

  for (int kt = 0; kt < 16; ++kt) {
    const int k0 = kt * 64;
    __syncthreads();
#pragma unroll
    for (int i = 0; i < 4; ++i) {  // A tile: 1024 16B chunks, 4/thread
      int c = w * 256 + i * 64 + l;
      int r = c >> 3, s = c & 7;
      gload_lds16(Ab + (size_t)(rowBase + r) * 1024 + k0 + ((s ^ (r & 7)) << 3),
                  At + (size_t)c * 8);
    }
#pragma unroll
    for (int i = 0; i < 2; ++i) {  // B tile: 512 chunks, 2/thread
      int c = w * 128 + i * 64 + l;
      int r = c >> 3, s = c & 7;
      gload_lds16(Wb + (size_t)(colBase + r) * 1024 + k0 + ((s ^ (r & 7)) << 3),
                  Bt + (size_t)c * 8);
    }
    __syncthreads();
#pragma unroll
    for (int kk = 0; kk < 2; ++kk) {
      short8 bfr[2];
#pragma unroll
      for (int n = 0; n < 2; ++n) {
        int br = wn * 32 + n * 16 + lr;
        int slot = (kk * 4 + lg) ^ (br & 7);
        bfr[n] = *reinterpret_cast<const short8*>(&Bt[br * 64 + slot * 8]);
      }
#pragma unroll
      for (int m = 0; m < 4; ++m) {
        int ar = wm * 64 + m * 16 + lr;
        int slot = (kk * 4 + lg) ^ (ar & 7);
        short8 afr = *reinterpret_cast<const short8*>(&At[ar * 64 + slot * 8]);
        acc[m][0] = __builtin_amdgcn_mfma_f32_16x16x32_bf16(afr, bfr[0], acc[m][0], 0, 0, 0);
        acc[m][1] = __builtin_amdgcn_mfma_f32_16x16x32_bf16(afr, bfr[1], acc[m][1], 0, 0, 0);
      }
    }
  }
#pragma unroll
  for (int m = 0; m < 4; ++m)
#pragma unroll
    for (int n = 0; n < 2; ++n) {
      int row0 = rowBase + wm * 64 + m * 16 + lg * 4;
      int col = colBase + wn * 32 + n * 16 + lr;
#pragma unroll
      for (int j = 0; j < 4; ++j) {
        float v = acc[m][n][j];
        if constexpr (sizeof(OutT) == 2)
          Cb[(size_t)(row0 + j) * 1024 + col] = (OutT)f2bf(v);
        else
          Cb[(size_t)(row0 + j) * 1024 + col] = (OutT)v;
      }
    }
}

// ---------- M[b][h] = K_bh^T V_bh / 8  (fp32, split-S atomics; Mb pre-zeroed) ----------
__global__ __launch_bounds__(256) void kv_outer(const short* __restrict__ Kp,
                                                const short* __restrict__ Vp,
                                                float* __restrict__ Mb) {
  __shared__ float Ks[128][64];
  __shared__ float Vs[128][64];
  const int t = threadIdx.x;
  const int sc = blockIdx.x, h = blockIdx.y, b = blockIdx.z;
  const size_t base = ((size_t)(b * 2048 + sc * 128)) * 1024 + h * 64;
  for (int e = t; e < 128 * 64; e += 256) {
    int r = e >> 6, c = e & 63;
    size_t g = base + (size_t)r * 1024 + c;
    Ks[r][c] = bf2f(Kp[g]);
    Vs[r][c] = bf2f(Vp[g]);
  }
  __syncthreads();
  const int dp0 = (t >> 4) * 4, d0 = (t & 15) * 4;
  float acc[4][4] = {};
  for (int s = 0; s < 128; ++s) {
    float4 kv = *reinterpret_cast<const float4*>(&Ks[s][dp0]);
    float4 vv = *reinterpret_cast<const float4*>(&Vs[s][d0]);
    float ka[4] = {kv.x, kv.y, kv.z, kv.w};
    float va[4] = {vv.x, vv.y, vv.z, vv.w};
#pragma unroll
    for (int i = 0; i < 4; ++i)
#pragma unroll
      for (int j = 0; j < 4; ++j) acc[i][j] += ka[i] * va[j];
  }
  float* dst = Mb + (size_t)(b * 16 + h) * 4096;
#pragma unroll
  for (int i = 0; i < 4; ++i)
#pragma unroll
    for (int j = 0; j < 4; ++j)
      atomicAdd(&dst[(dp0 + i) * 64 + d0 + j], acc[i][j] * 0.125f);
}

// ---------- W2T[b][j][h*64+d'] = sum_d M_bh[d'][d] * Wo[j][h*64+d]  (bf16 out) ----------
__global__ __launch_bounds__(256) void make_w2t(const float* __restrict__ Mb,
                                                const short* __restrict__ Wo,
                                                short* __restrict__ W2T) {
  __shared__ float Ms[64][65];
  __shared__ float Wos[64][64];
  const int t = threadIdx.x;
  const int jc = blockIdx.x, h = blockIdx.y, b = blockIdx.z;
  const float* Msrc = Mb + (size_t)(b * 16 + h) * 4096;
  for (int e = t; e < 4096; e += 256) {
    int r = e >> 6, c = e & 63;
    Ms[r][c] = Msrc[e];
    Wos[r][c] = bf2f(Wo[(size_t)(jc * 64 + r) * 1024 + h * 64 + c]);
  }
  __syncthreads();
  const int j0 = (t >> 4) * 4, p0 = (t & 15) * 4;
  float acc[4][4] = {};
  for (int d = 0; d < 64; ++d) {
    float wv[4], mv[4];
#pragma unroll
    for (int i = 0; i < 4; ++i) { wv[i] = Wos[j0 + i][d]; mv[i] = Ms[p0 + i][d]; }
#pragma unroll
    for (int i = 0; i < 4; ++i)
#pragma unroll
      for (int j2 = 0; j2 < 4; ++j2) acc[i][j2] += wv[i] * mv[j2];
  }
  short* dst = W2T + (size_t)b * 1048576;
#pragma unroll
  for (int i = 0; i < 4; ++i)
#pragma unroll
    for (int j2 = 0; j2 < 4; ++j2)
      dst[(size_t)(jc * 64 + j0 + i) * 1024 + h * 64 + p0 + j2] = f2bf(acc[i][j2]);
}

extern "C" void kernel_launch(void* const* d_in, const int* in_sizes, int n_in,
                              void* d_out, int out_size, void* d_ws, size_t ws_size,
                              hipStream_t stream) {
  const float* q  = (const float*)d_in[0];
  const float* k  = (const float*)d_in[1];
  const float* v  = (const float*)d_in[2];
  // d_in[3] = mask: no-op in the reference
  const float* Wq = (const float*)d_in[4];
  const float* Wk = (const float*)d_in[5];
  const float* Wv = (const float*)d_in[6];
  const float* Wo = (const float*)d_in[7];
  float* out = (float*)d_out;
  char* ws = (char*)d_ws;

  // workspace layout (~62 MiB)
  short* qkv = (short*)(ws);                  // 24 MiB: q,k,v bf16 contiguous (4M elems each)
  short* qb = qkv;
  short* kb = qkv + (size_t)4194304;
  short* vb = qkv + (size_t)8388608;
  short* wb = (short*)(ws + (24l << 20));     // 8 MiB: Wq,Wk,Wv,Wo bf16 (1M elems each)
  short* wqb = wb;
  short* wkb = wb + 1048576;
  short* wvb = wb + 2097152;
  short* wob = wb + 3145728;
  short* Pp = (short*)(ws + (32l << 20));     // 24 MiB: Qp,Kp,Vp contiguous
  short* Qp = Pp;
  short* Kp = Pp + (size_t)4194304;
  short* Vp = Pp + (size_t)8388608;
  float* Mb  = (float*)(ws + (56l << 20));    // 512 KiB
  short* W2T = (short*)(ws + (57l << 20));    // 4 MiB

  // 1) convert everything to bf16 + zero Mb (2097152 cvt groups + 16384 zero groups)
  cvt_all<<<8256, 256, 0, stream>>>(q, k, v, Wq, Wk, Wv, Wo,
                                    qb, kb, vb, wqb, wkb, wvb, wob, Mb);

  // 2) Q/K/V projections in one z-batched launch (768 blocks = 3/CU)
  gemm_bt128<short><<<dim3(8, 32, 3), 256, 0, stream>>>(
      qkv, wb, Pp, 4194304l, 1048576l, 4194304l);

  // 3) per-head K^T V / 8
  kv_outer<<<dim3(16, 16, 2), 256, 0, stream>>>(Kp, Vp, Mb);

  // 4) fold blockdiag(M) into Wo
  make_w2t<<<dim3(16, 16, 2), 256, 0, stream>>>(Mb, wob, W2T);

  // 5) out[b] = Qp[b] @ W2T[b]^T  (128x64 tile -> 512 blocks = 2/CU)
  gemm_bt64<float><<<dim3(16, 16, 2), 256, 0, stream>>>(
      Qp, W2T, out, 2097152l, 1048576l, 2097152l);
}

// Round 4
// 209.052 us; speedup vs baseline: 1.2433x; 1.0163x over previous
//
#include <hip/hip_runtime.h>

#define DEV __device__ __forceinline__

typedef __attribute__((ext_vector_type(8))) short short8;
typedef __attribute__((ext_vector_type(4))) float f32x4;

DEV short f2bf(float x) {
  unsigned u = __float_as_uint(x);
  unsigned r = (u + 0x7fffu + ((u >> 16) & 1u)) >> 16;
  return (short)r;
}
DEV float bf2f(short x) {
  return __uint_as_float(((unsigned)(unsigned short)x) << 16);
}

DEV void gload_lds16(const void* g, void* l) {
  __builtin_amdgcn_global_load_lds((const __attribute__((address_space(1))) void*)g,
                                   (__attribute__((address_space(3))) void*)l, 16, 0, 0);
}

// ---------- fused fp32 -> bf16 convert for all 7 tensors + zero-init of Mb ----------
__global__ __launch_bounds__(256) void cvt_all(
    const float* __restrict__ s0, const float* __restrict__ s1,
    const float* __restrict__ s2, const float* __restrict__ s3,
    const float* __restrict__ s4, const float* __restrict__ s5,
    const float* __restrict__ s6,
    short* __restrict__ d0, short* __restrict__ d1, short* __restrict__ d2,
    short* __restrict__ d3, short* __restrict__ d4, short* __restrict__ d5,
    short* __restrict__ d6, float* __restrict__ Mb) {
  int g = blockIdx.x * 256 + threadIdx.x;
  if (g >= 2097152) {  // Mb zero-init (kv_outer atomics need zeros; ws is poisoned 0xAA)
    int off = g - 2097152;
    float4 z = {0.f, 0.f, 0.f, 0.f};
    float4* p = reinterpret_cast<float4*>(Mb) + (size_t)off * 2;
    p[0] = z;
    p[1] = z;
    return;
  }
  const float* s;
  short* d;
  int off;
  if (g < 524288) { s = s0; d = d0; off = g; }
  else if (g < 1048576) { s = s1; d = d1; off = g - 524288; }
  else if (g < 1572864) { s = s2; d = d2; off = g - 1048576; }
  else {
    int w2 = g - 1572864;
    int seg = w2 >> 17;
    off = w2 & 131071;
    s = seg == 0 ? s3 : seg == 1 ? s4 : seg == 2 ? s5 : s6;
    d = seg == 0 ? d3 : seg == 1 ? d4 : seg == 2 ? d5 : d6;
  }
  const float4* p = reinterpret_cast<const float4*>(s) + (size_t)off * 2;
  float4 a = p[0], b = p[1];
  short8 o;
  o[0] = f2bf(a.x); o[1] = f2bf(a.y); o[2] = f2bf(a.z); o[3] = f2bf(a.w);
  o[4] = f2bf(b.x); o[5] = f2bf(b.y); o[6] = f2bf(b.z); o[7] = f2bf(b.w);
  *reinterpret_cast<short8*>(d + (size_t)off * 8) = o;
}

// ---------- bf16 MFMA GEMM, 128x64 tile: C[M,1024] = A[M,1024] @ W[1024,1024]^T ----------
// BM=128 BN=64 BK=64; 256 threads = 4 waves (2x2); wave tile 64x32 (4x2 frags of 16x16x32).
// 24 KB LDS -> 6 blocks/CU; ~64 VGPR. z-batched via element strides.
// XCD-chunked swizzle: consecutive logical tiles (sharing the A row-panel, col-fastest)
// land on the SAME XCD -> A-panel fetched once per XCD, W stays L2-resident.
// LDS row-major [row][64] bf16, k-slot (16B) XOR-swizzle by (row&7): linear gload_lds
// dest + inverse-swizzled global src + same-swizzled ds_read (involution both sides).
template <typename OutT>
__global__ __launch_bounds__(256) void gemm_bt64(const short* __restrict__ A,
                                                 const short* __restrict__ W,
                                                 OutT* __restrict__ C,
                                                 long strideA, long strideW, long strideC) {
  __shared__ short At[128 * 64];
  __shared__ short Bt[64 * 64];
  // XCD swizzle (valid: grid size % 8 == 0 for all our launches)
  const int nx = gridDim.x, ny = gridDim.y;
  int flat = blockIdx.x + nx * (blockIdx.y + ny * blockIdx.z);
  int nwg = nx * ny * gridDim.z;
  int l2 = (flat & 7) * (nwg >> 3) + (flat >> 3);
  int colB = l2 % nx;
  int tmp = l2 / nx;
  int rowB = tmp % ny;
  int zB = tmp / ny;

  const short* Ab = A + (size_t)zB * strideA;
  const short* Wb = W + (size_t)zB * strideW;
  OutT* Cb = C + (size_t)zB * strideC;
  const int t = threadIdx.x;
  const int w = t >> 6;
  const int l = t & 63;
  const int lg = l >> 4, lr = l & 15;
  const int wm = w >> 1, wn = w & 1;
  const int rowBase = rowB * 128;
  const int colBase = colB * 64;

  f32x4 acc[4][2] = {};

  for (int kt = 0; kt < 16; ++kt) {
    const int k0 = kt * 64;
    __syncthreads();  // previous iter's LDS reads done
#pragma unroll
    for (int i = 0; i < 4; ++i) {  // A tile: 1024 16B chunks, 4/thread
      int c = w * 256 + i * 64 + l;
      int r = c >> 3, s = c & 7;
      gload_lds16(Ab + (size_t)(rowBase + r) * 1024 + k0 + ((s ^ (r & 7)) << 3),
                  At + (size_t)c * 8);
    }
#pragma unroll
    for (int i = 0; i < 2; ++i) {  // B tile: 512 chunks, 2/thread
      int c = w * 128 + i * 64 + l;
      int r = c >> 3, s = c & 7;
      gload_lds16(Wb + (size_t)(colBase + r) * 1024 + k0 + ((s ^ (r & 7)) << 3),
                  Bt + (size_t)c * 8);
    }
    __syncthreads();  // compiler drains vmcnt(0) before barrier -> tiles ready
#pragma unroll
    for (int kk = 0; kk < 2; ++kk) {
      short8 bfr[2];
#pragma unroll
      for (int n = 0; n < 2; ++n) {
        int br = wn * 32 + n * 16 + lr;
        int slot = (kk * 4 + lg) ^ (br & 7);
        bfr[n] = *reinterpret_cast<const short8*>(&Bt[br * 64 + slot * 8]);
      }
#pragma unroll
      for (int m = 0; m < 4; ++m) {
        int ar = wm * 64 + m * 16 + lr;
        int slot = (kk * 4 + lg) ^ (ar & 7);
        short8 afr = *reinterpret_cast<const short8*>(&At[ar * 64 + slot * 8]);
        acc[m][0] = __builtin_amdgcn_mfma_f32_16x16x32_bf16(afr, bfr[0], acc[m][0], 0, 0, 0);
        acc[m][1] = __builtin_amdgcn_mfma_f32_16x16x32_bf16(afr, bfr[1], acc[m][1], 0, 0, 0);
      }
    }
  }
  // epilogue: C/D layout col = lane&15, row = (lane>>4)*4 + j
#pragma unroll
  for (int m = 0; m < 4; ++m)
#pragma unroll
    for (int n = 0; n < 2; ++n) {
      int row0 = rowBase + wm * 64 + m * 16 + lg * 4;
      int col = colBase + wn * 32 + n * 16 + lr;
#pragma unroll
      for (int j = 0; j < 4; ++j) {
        float v = acc[m][n][j];
        if constexpr (sizeof(OutT) == 2)
          Cb[(size_t)(row0 + j) * 1024 + col] = (OutT)f2bf(v);
        else
          Cb[(size_t)(row0 + j) * 1024 + col] = (OutT)v;
      }
    }
}

// ---------- M[b][h] = K_bh^T V_bh / 8  (fp32, split-S atomics; Mb pre-zeroed) ----------
__global__ __launch_bounds__(256) void kv_outer(const short* __restrict__ Kp,
                                                const short* __restrict__ Vp,
                                                float* __restrict__ Mb) {
  __shared__ float Ks[128][64];
  __shared__ float Vs[128][64];
  const int t = threadIdx.x;
  const int sc = blockIdx.x, h = blockIdx.y, b = blockIdx.z;
  const size_t base = ((size_t)(b * 2048 + sc * 128)) * 1024 + h * 64;
  for (int e = t; e < 128 * 64; e += 256) {
    int r = e >> 6, c = e & 63;
    size_t g = base + (size_t)r * 1024 + c;
    Ks[r][c] = bf2f(Kp[g]);
    Vs[r][c] = bf2f(Vp[g]);
  }
  __syncthreads();
  const int dp0 = (t >> 4) * 4, d0 = (t & 15) * 4;
  float acc[4][4] = {};
  for (int s = 0; s < 128; ++s) {
    float4 kv = *reinterpret_cast<const float4*>(&Ks[s][dp0]);
    float4 vv = *reinterpret_cast<const float4*>(&Vs[s][d0]);
    float ka[4] = {kv.x, kv.y, kv.z, kv.w};
    float va[4] = {vv.x, vv.y, vv.z, vv.w};
#pragma unroll
    for (int i = 0; i < 4; ++i)
#pragma unroll
      for (int j = 0; j < 4; ++j) acc[i][j] += ka[i] * va[j];
  }
  float* dst = Mb + (size_t)(b * 16 + h) * 4096;
#pragma unroll
  for (int i = 0; i < 4; ++i)
#pragma unroll
    for (int j = 0; j < 4; ++j)
      atomicAdd(&dst[(dp0 + i) * 64 + d0 + j], acc[i][j] * 0.125f);
}

// ---------- W2T[b][j][h*64+d'] = sum_d M_bh[d'][d] * Wo[j][h*64+d]  (bf16 out) ----------
__global__ __launch_bounds__(256) void make_w2t(const float* __restrict__ Mb,
                                                const short* __restrict__ Wo,
                                                short* __restrict__ W2T) {
  __shared__ float Ms[64][65];
  __shared__ float Wos[64][64];
  const int t = threadIdx.x;
  const int jc = blockIdx.x, h = blockIdx.y, b = blockIdx.z;
  const float* Msrc = Mb + (size_t)(b * 16 + h) * 4096;
  for (int e = t; e < 4096; e += 256) {
    int r = e >> 6, c = e & 63;
    Ms[r][c] = Msrc[e];
    Wos[r][c] = bf2f(Wo[(size_t)(jc * 64 + r) * 1024 + h * 64 + c]);
  }
  __syncthreads();
  const int j0 = (t >> 4) * 4, p0 = (t & 15) * 4;
  float acc[4][4] = {};
  for (int d = 0; d < 64; ++d) {
    float wv[4], mv[4];
#pragma unroll
    for (int i = 0; i < 4; ++i) { wv[i] = Wos[j0 + i][d]; mv[i] = Ms[p0 + i][d]; }
#pragma unroll
    for (int i = 0; i < 4; ++i)
#pragma unroll
      for (int j2 = 0; j2 < 4; ++j2) acc[i][j2] += wv[i] * mv[j2];
  }
  short* dst = W2T + (size_t)b * 1048576;
#pragma unroll
  for (int i = 0; i < 4; ++i)
#pragma unroll
    for (int j2 = 0; j2 < 4; ++j2)
      dst[(size_t)(jc * 64 + j0 + i) * 1024 + h * 64 + p0 + j2] = f2bf(acc[i][j2]);
}

extern "C" void kernel_launch(void* const* d_in, const int* in_sizes, int n_in,
                              void* d_out, int out_size, void* d_ws, size_t ws_size,
                              hipStream_t stream) {
  const float* q  = (const float*)d_in[0];
  const float* k  = (const float*)d_in[1];
  const float* v  = (const float*)d_in[2];
  // d_in[3] = mask: no-op in the reference
  const float* Wq = (const float*)d_in[4];
  const float* Wk = (const float*)d_in[5];
  const float* Wv = (const float*)d_in[6];
  const float* Wo = (const float*)d_in[7];
  float* out = (float*)d_out;
  char* ws = (char*)d_ws;

  // workspace layout (~62 MiB)
  short* qkv = (short*)(ws);                  // 24 MiB: q,k,v bf16 contiguous (4M elems each)
  short* qb = qkv;
  short* kb = qkv + (size_t)4194304;
  short* vb = qkv + (size_t)8388608;
  short* wb = (short*)(ws + (24l << 20));     // 8 MiB: Wq,Wk,Wv,Wo bf16 (1M elems each)
  short* wqb = wb;
  short* wkb = wb + 1048576;
  short* wvb = wb + 2097152;
  short* wob = wb + 3145728;
  short* Pp = (short*)(ws + (32l << 20));     // 24 MiB: Qp,Kp,Vp contiguous
  short* Qp = Pp;
  short* Kp = Pp + (size_t)4194304;
  short* Vp = Pp + (size_t)8388608;
  float* Mb  = (float*)(ws + (56l << 20));    // 512 KiB
  short* W2T = (short*)(ws + (57l << 20));    // 4 MiB

  // 1) convert everything to bf16 + zero Mb
  cvt_all<<<8256, 256, 0, stream>>>(q, k, v, Wq, Wk, Wv, Wo,
                                    qb, kb, vb, wqb, wkb, wvb, wob, Mb);

  // 2) Q/K/V projections, one z-batched launch: 16x32x3 = 1536 blocks = 6/CU
  gemm_bt64<short><<<dim3(16, 32, 3), 256, 0, stream>>>(
      qkv, wb, Pp, 4194304l, 1048576l, 4194304l);

  // 3) per-head K^T V / 8
  kv_outer<<<dim3(16, 16, 2), 256, 0, stream>>>(Kp, Vp, Mb);

  // 4) fold blockdiag(M) into Wo
  make_w2t<<<dim3(16, 16, 2), 256, 0, stream>>>(Mb, wob, W2T);

  // 5) out[b] = Qp[b] @ W2T[b]^T  (512 blocks = 2/CU)
  gemm_bt64<float><<<dim3(16, 16, 2), 256, 0, stream>>>(
      Qp, W2T, out, 2097152l, 1048576l, 2097152l);
}